// Round 1
// baseline (76.595 us; speedup 1.0000x reference)
//
#include <hip/hip_runtime.h>
#include <hip/hip_bf16.h>
#include <stdint.h>

#define HW 16384   // H*W
#define C 128
#define NPIX_BLOCK 128   // pixels per block (4 waves x 2 strips x 16)

typedef __attribute__((ext_vector_type(8))) short bf16x8;
typedef __attribute__((ext_vector_type(4))) float f32x4;

__device__ __forceinline__ uint16_t bf16_rne(float f) {
    uint32_t u = __builtin_bit_cast(uint32_t, f);
    u += 0x7FFFu + ((u >> 16) & 1u);
    return (uint16_t)(u >> 16);
}

// ---------------------------------------------------------------------------
// Kernel 1: pack gamma (f32 [128][128]) into bf16 MFMA A-fragment order.
// ws layout: ushort gfrag[8 ot][4 ks][64 lane][8 j]
//   element = gamma[o = 16*ot + (lane&15)][c = 32*ks + 8*(lane>>4) + j]
// ---------------------------------------------------------------------------
__global__ void gdn_prep_gamma(const float* __restrict__ gamma,
                               uint16_t* __restrict__ gws) {
    int t = blockIdx.x * 256 + threadIdx.x;   // 0..2047, one 16B frag-block each
    int l  = t & 63;
    int ks = (t >> 6) & 3;
    int ot = t >> 8;
    int o  = (ot << 4) | (l & 15);
    int c0 = (ks << 5) + ((l >> 4) << 3);
    const float* gp = gamma + o * C + c0;
    bf16x8 v;
#pragma unroll
    for (int j = 0; j < 8; ++j) v[j] = (short)bf16_rne(gp[j]);
    *reinterpret_cast<bf16x8*>(gws + (size_t)t * 8) = v;
}

// ---------------------------------------------------------------------------
// Main kernel: one block = 128 consecutive pixels of one image.
// Wave w handles 2 strips of 16 pixels, all 128 output channels via
// 16x16x32 bf16 MFMA. acc initialized with beta (free C-input).
// ---------------------------------------------------------------------------
__global__ __launch_bounds__(256, 3)
void gdn_main(const float* __restrict__ x, const float* __restrict__ gamma,
              const float* __restrict__ beta, float* __restrict__ out,
              const uint16_t* __restrict__ gws) {
    __shared__ uint16_t gfrag[16384];  // 32 KB: [ot][ks][lane][j]

    const int tid = threadIdx.x;

    // ---- stage gamma fragments into LDS (linear, conflict-free) ----
    if (gws) {
#pragma unroll
        for (int it = 0; it < 8; ++it) {
            int i = tid + it * 256;
            *reinterpret_cast<bf16x8*>(&gfrag[i * 8]) =
                *reinterpret_cast<const bf16x8*>(gws + i * 8);
        }
    } else {
        // fallback: build frags from fp32 gamma directly (L2-resident)
#pragma unroll
        for (int it = 0; it < 8; ++it) {
            int flat = tid + it * 256;          // 0..2047
            int o = flat & 127, c8 = flat >> 7; // o fast -> conflict-light writes
            int ks = c8 >> 2;
            int lw = ((c8 & 3) << 4) | (o & 15);
            const float* gp = gamma + o * C + c8 * 8;
            bf16x8 v;
#pragma unroll
            for (int j = 0; j < 8; ++j) v[j] = (short)bf16_rne(gp[j]);
            *reinterpret_cast<bf16x8*>(&gfrag[(((o >> 4) * 4 + ks) * 64 + lw) * 8]) = v;
        }
    }
    __syncthreads();

    const int lane = tid & 63;
    const int w    = tid >> 6;
    const int b    = blockIdx.x >> 7;                 // image index (128 blocks/image)
    const int pblk = (blockIdx.x & 127) * NPIX_BLOCK + w * 32;
    const float* xb = x   + (size_t)b * C * HW;
    float*       ob = out + (size_t)b * C * HW;

    const int lp = lane & 15;   // pixel within strip (n index)
    const int lg = lane >> 4;   // lane group 0..3

    // ---- acc init = beta (folded into MFMA C-input) ----
    f32x4 acc[2][8];
    {
#pragma unroll
        for (int ot = 0; ot < 8; ++ot) {
            f32x4 bv = *reinterpret_cast<const f32x4*>(beta + ot * 16 + lg * 4);
            acc[0][ot] = bv;
            acc[1][ot] = bv;
        }
    }

    // ---- build B fragments (x^2 in bf16) straight from global ----
    bf16x8 bfr[2][4];
#pragma unroll
    for (int s = 0; s < 2; ++s) {
        const int p = pblk + s * 16 + lp;
#pragma unroll
        for (int ks = 0; ks < 4; ++ks) {
            const float* xp = xb + (ks * 32 + lg * 8) * HW + p;
            float v[8];
#pragma unroll
            for (int j = 0; j < 8; ++j) v[j] = xp[j * HW];
#pragma unroll
            for (int j = 0; j < 8; ++j) bfr[s][ks][j] = (short)bf16_rne(v[j] * v[j]);
        }
    }

    // ---- MFMA: norm[o][p] = gamma @ xsq + beta ----
#pragma unroll
    for (int ks = 0; ks < 4; ++ks) {
#pragma unroll
        for (int ot = 0; ot < 8; ++ot) {
            bf16x8 a = *reinterpret_cast<const bf16x8*>(
                &gfrag[((ot * 4 + ks) * 64 + lane) * 8]);
            acc[0][ot] = __builtin_amdgcn_mfma_f32_16x16x32_bf16(a, bfr[0][ks], acc[0][ot], 0, 0, 0);
            acc[1][ot] = __builtin_amdgcn_mfma_f32_16x16x32_bf16(a, bfr[1][ks], acc[1][ot], 0, 0, 0);
        }
    }

    // ---- epilogue: out = x * rsqrt(norm); x re-read is L1/L2-hot ----
#pragma unroll
    for (int s = 0; s < 2; ++s) {
        const int p = pblk + s * 16 + lp;
#pragma unroll
        for (int ot = 0; ot < 8; ++ot) {
            const int o0 = ot * 16 + lg * 4;
#pragma unroll
            for (int r = 0; r < 4; ++r) {
                float xv = xb[(o0 + r) * HW + p];
                ob[(o0 + r) * HW + p] = xv * rsqrtf(acc[s][ot][r]);
            }
        }
    }
}

extern "C" void kernel_launch(void* const* d_in, const int* in_sizes, int n_in,
                              void* d_out, int out_size, void* d_ws, size_t ws_size,
                              hipStream_t stream) {
    const float* x     = (const float*)d_in[0];
    const float* gamma = (const float*)d_in[1];
    const float* beta  = (const float*)d_in[2];
    float* out = (float*)d_out;

    uint16_t* gws = (d_ws && ws_size >= 32768) ? (uint16_t*)d_ws : nullptr;
    if (gws) {
        gdn_prep_gamma<<<8, 256, 0, stream>>>(gamma, gws);
    }
    // 16 images * 128 blocks/image = 2048 blocks
    gdn_main<<<2048, 256, 0, stream>>>(x, gamma, beta, out, gws);
}